// Round 1
// baseline (483.993 us; speedup 1.0000x reference)
//
#include <hip/hip_runtime.h>

#define D 128

// ---------------- setup kernels: degree, rsqrt, CSR build ----------------

__global__ __launch_bounds__(256) void zero_int(int* __restrict__ a, int len) {
    int i = blockIdx.x * 256 + threadIdx.x;
    if (i < len) a[i] = 0;
}

// cnt2 = [cnt_normal (n) | cnt_role (n)]
__global__ __launch_bounds__(256) void count_deg(const int* __restrict__ dst_n, int En,
                                                 const int* __restrict__ dst_r, int Er,
                                                 int* __restrict__ cnt2, int n) {
    int i = blockIdx.x * 256 + threadIdx.x;
    if (i < En) {
        atomicAdd(&cnt2[dst_n[i]], 1);
    } else if (i < En + Er) {
        atomicAdd(&cnt2[n + dst_r[i - En]], 1);
    }
}

// dis = rsqrt(deg), deg = in-degree + 1 (self loop)
__global__ __launch_bounds__(256) void compute_dis(const int* __restrict__ cnt2,
                                                   float* __restrict__ dis2, int len) {
    int i = blockIdx.x * 256 + threadIdx.x;
    if (i < len) dis2[i] = rsqrtf((float)(cnt2[i] + 1));
}

// scan pass 1: per-1024-chunk sums.  grid = 2*nb blocks (two graphs).
__global__ __launch_bounds__(1024) void scan_pass1(const int* __restrict__ cnt2,
                                                   int* __restrict__ bsum2, int n, int nb) {
    int g = blockIdx.x / nb, b = blockIdx.x % nb;
    int i = b * 1024 + threadIdx.x;
    int v = (i < n) ? cnt2[g * n + i] : 0;
    #pragma unroll
    for (int off = 32; off; off >>= 1) v += __shfl_down(v, off, 64);
    __shared__ int wsum[16];
    int lane = threadIdx.x & 63, wid = threadIdx.x >> 6;
    if (lane == 0) wsum[wid] = v;
    __syncthreads();
    if (threadIdx.x == 0) {
        int s = 0;
        for (int w = 0; w < 16; ++w) s += wsum[w];
        bsum2[g * 64 + b] = s;
    }
}

// scan pass 2: exclusive-scan the <=64 chunk sums per graph (wave 0 = graph 0, wave 1 = graph 1)
__global__ __launch_bounds__(128) void scan_pass2(int* __restrict__ bsum2, int nb) {
    int wid = threadIdx.x >> 6, lane = threadIdx.x & 63;
    int v = (lane < nb) ? bsum2[wid * 64 + lane] : 0;
    int incl = v;
    #pragma unroll
    for (int off = 1; off < 64; off <<= 1) {
        int t = __shfl_up(incl, off, 64);
        if (lane >= off) incl += t;
    }
    if (lane < nb) bsum2[wid * 64 + lane] = incl - v;  // exclusive
}

// scan pass 3: full exclusive scan -> row_start + cursor
__global__ __launch_bounds__(1024) void scan_pass3(const int* __restrict__ cnt2,
                                                   const int* __restrict__ bsum2,
                                                   int* __restrict__ rs2, int* __restrict__ cur2,
                                                   int n, int nb, int En, int Er) {
    int g = blockIdx.x / nb, b = blockIdx.x % nb;
    int i = b * 1024 + threadIdx.x;
    int v = (i < n) ? cnt2[g * n + i] : 0;
    int lane = threadIdx.x & 63, wid = threadIdx.x >> 6;
    int incl = v;
    #pragma unroll
    for (int off = 1; off < 64; off <<= 1) {
        int t = __shfl_up(incl, off, 64);
        if (lane >= off) incl += t;
    }
    __shared__ int wsum[16];
    if (lane == 63) wsum[wid] = incl;
    __syncthreads();
    if (threadIdx.x == 0) {
        int s = 0;
        for (int w = 0; w < 16; ++w) { int t = wsum[w]; wsum[w] = s; s += t; }
    }
    __syncthreads();
    int excl = incl - v + wsum[wid] + bsum2[g * 64 + b];
    if (i < n) {
        rs2[g * (n + 1) + i] = excl;
        cur2[g * n + i] = excl;
    }
    if (i == 0) rs2[g * (n + 1) + n] = g ? Er : En;
}

// scatter src ids into CSR slots (per-graph-local offsets)
__global__ __launch_bounds__(256) void scatter_edges(const int* __restrict__ src_n,
                                                     const int* __restrict__ dst_n, int En,
                                                     const int* __restrict__ src_r,
                                                     const int* __restrict__ dst_r, int Er,
                                                     int* __restrict__ cur2,
                                                     int* __restrict__ csr, int n) {
    int i = blockIdx.x * 256 + threadIdx.x;
    if (i < En) {
        int p = atomicAdd(&cur2[dst_n[i]], 1);
        csr[p] = src_n[i];
    } else if (i < En + Er) {
        int j = i - En;
        int p = atomicAdd(&cur2[n + dst_r[j]], 1);
        csr[En + p] = src_r[j];
    }
}

// ---------------- per-layer kernels ----------------

// Y[v,:] = dis[v] * (X[v,:] @ W)   (fp32; 64-row tile in LDS, 8x4 register tile/thread)
__global__ __launch_bounds__(256) void gemm_scale(const float* __restrict__ X,
                                                  const float* __restrict__ W,
                                                  const float* __restrict__ dis,
                                                  float* __restrict__ Y, int n) {
    __shared__ float sX[64 * D];  // 32 KB
    int t = threadIdx.x;
    int cg = (t & 31) << 2;   // column group: 4 cols
    int r0 = (t >> 5) << 3;   // row group: 8 rows
    for (int rb = blockIdx.x * 64; rb < n; rb += gridDim.x * 64) {
        int rows = min(64, n - rb);
        for (int i = t; i < rows * 32; i += 256)
            ((float4*)sX)[i] = ((const float4*)X)[(size_t)rb * 32 + i];
        __syncthreads();
        float acc[8][4] = {};
        #pragma unroll 4
        for (int k = 0; k < D; ++k) {
            float4 w = *(const float4*)(W + (size_t)k * D + cg);
            #pragma unroll
            for (int r = 0; r < 8; ++r) {
                float xv = sX[(r0 + r) * D + k];
                acc[r][0] += xv * w.x;
                acc[r][1] += xv * w.y;
                acc[r][2] += xv * w.z;
                acc[r][3] += xv * w.w;
            }
        }
        #pragma unroll
        for (int r = 0; r < 8; ++r) {
            int row = rb + r0 + r;
            if (row < n) {
                float dv = dis[row];
                float4 o;
                o.x = acc[r][0] * dv; o.y = acc[r][1] * dv;
                o.z = acc[r][2] * dv; o.w = acc[r][3] * dv;
                *(float4*)(Y + (size_t)row * D + cg) = o;
            }
        }
        __syncthreads();
    }
}

// out[v,:] = maybe_relu( dis[v] * (sum_{e in CSR(v)} g[src_e,:] + g[v,:]) + bias )
// one 64-lane wave per node, float2 per lane (512B row per load)
__global__ __launch_bounds__(256) void aggregate(const float* __restrict__ g,
                                                 const int* __restrict__ rs,
                                                 const int* __restrict__ csr,
                                                 const float* __restrict__ dis,
                                                 const float* __restrict__ bias,
                                                 float* __restrict__ out, int n, int do_relu) {
    int v = blockIdx.x * 4 + (threadIdx.x >> 6);
    if (v >= n) return;
    int lane = threadIdx.x & 63;
    const float2* g2 = (const float2*)g;
    float2 acc = g2[(size_t)v * 64 + lane];  // self loop (dis[v]*h[v] pre-scaled)
    int e = rs[v], end = rs[v + 1];
    for (; e + 3 < end; e += 4) {
        int s0 = csr[e], s1 = csr[e + 1], s2 = csr[e + 2], s3 = csr[e + 3];
        float2 m0 = g2[(size_t)s0 * 64 + lane];
        float2 m1 = g2[(size_t)s1 * 64 + lane];
        float2 m2 = g2[(size_t)s2 * 64 + lane];
        float2 m3 = g2[(size_t)s3 * 64 + lane];
        acc.x += m0.x + m1.x + m2.x + m3.x;
        acc.y += m0.y + m1.y + m2.y + m3.y;
    }
    for (; e < end; ++e) {
        int s = csr[e];
        float2 m = g2[(size_t)s * 64 + lane];
        acc.x += m.x;
        acc.y += m.y;
    }
    float dv = dis[v];
    float2 bb = ((const float2*)bias)[lane];
    float ox = dv * acc.x + bb.x;
    float oy = dv * acc.y + bb.y;
    if (do_relu) { ox = fmaxf(ox, 0.f); oy = fmaxf(oy, 0.f); }
    ((float2*)out)[(size_t)v * 64 + lane] = make_float2(ox, oy);
}

// ---------------- host launcher ----------------

extern "C" void kernel_launch(void* const* d_in, const int* in_sizes, int n_in,
                              void* d_out, int out_size, void* d_ws, size_t ws_size,
                              hipStream_t stream) {
    const float* x      = (const float*)d_in[0];
    const float* W_role = (const float*)d_in[1];
    const float* b_role = (const float*)d_in[2];
    const float* W2     = (const float*)d_in[3];
    const float* b2     = (const float*)d_in[4];
    const float* W1     = (const float*)d_in[5];
    const float* b1     = (const float*)d_in[6];
    const int*   ein    = (const int*)d_in[7];
    const int*   eir    = (const int*)d_in[8];

    int n  = in_sizes[0] / D;   // 50000
    int En = in_sizes[7] / 2;   // 640000
    int Er = in_sizes[8] / 2;   // 640000
    const int* src_n = ein;
    const int* dst_n = ein + En;
    const int* src_r = eir;
    const int* dst_r = eir + Er;
    float* out = (float*)d_out;

    // workspace carve-up (~32.3 MB total)
    char* p = (char*)d_ws;
    auto alloc = [&](size_t bytes) { char* r = p; p += (bytes + 255) & ~(size_t)255; return r; };
    float* g    = (float*)alloc((size_t)n * D * sizeof(float));   // 25.6 MB
    int*   cnt2 = (int*)alloc((size_t)2 * n * sizeof(int));
    float* dis2 = (float*)alloc((size_t)2 * n * sizeof(float));
    int*   rs2  = (int*)alloc((size_t)2 * (n + 1) * sizeof(int));
    int*   cur2 = (int*)alloc((size_t)2 * n * sizeof(int));
    int*   bsum2= (int*)alloc(128 * sizeof(int));
    int*   csr  = (int*)alloc((size_t)(En + Er) * sizeof(int));   // 5.12 MB
    float* dis_n = dis2;
    float* dis_r = dis2 + n;
    int*   rs_n  = rs2;
    int*   rs_r  = rs2 + (n + 1);
    int*   csr_n = csr;
    int*   csr_r = csr + En;

    int nb = (n + 1023) / 1024;  // 49 (must be <= 64)

    // ---- graph preprocessing (both graphs fused per dispatch) ----
    zero_int<<<(2 * n + 255) / 256, 256, 0, stream>>>(cnt2, 2 * n);
    count_deg<<<(En + Er + 255) / 256, 256, 0, stream>>>(dst_n, En, dst_r, Er, cnt2, n);
    compute_dis<<<(2 * n + 255) / 256, 256, 0, stream>>>(cnt2, dis2, 2 * n);
    scan_pass1<<<2 * nb, 1024, 0, stream>>>(cnt2, bsum2, n, nb);
    scan_pass2<<<1, 128, 0, stream>>>(bsum2, nb);
    scan_pass3<<<2 * nb, 1024, 0, stream>>>(cnt2, bsum2, rs2, cur2, n, nb, En, Er);
    scatter_edges<<<(En + Er + 255) / 256, 256, 0, stream>>>(src_n, dst_n, En, src_r, dst_r, Er,
                                                             cur2, csr, n);

    // ---- 3 GCN layers; d_out doubles as the h scratch buffer ----
    int gblk = (n + 63) / 64;
    int ablk = (n + 3) / 4;
    // layer 1: role graph, relu
    gemm_scale<<<gblk, 256, 0, stream>>>(x, W_role, dis_r, g, n);
    aggregate<<<ablk, 256, 0, stream>>>(g, rs_r, csr_r, dis_r, b_role, out, n, 1);
    // layer 2: normal graph, relu
    gemm_scale<<<gblk, 256, 0, stream>>>(out, W2, dis_n, g, n);
    aggregate<<<ablk, 256, 0, stream>>>(g, rs_n, csr_n, dis_n, b2, out, n, 1);
    // layer 3: normal graph, no relu
    gemm_scale<<<gblk, 256, 0, stream>>>(out, W1, dis_n, g, n);
    aggregate<<<ablk, 256, 0, stream>>>(g, rs_n, csr_n, dis_n, b1, out, n, 0);
}

// Round 2
// 466.413 us; speedup vs baseline: 1.0377x; 1.0377x over previous
//
#include <hip/hip_runtime.h>

#define D 128

// ---------------- graph preprocessing ----------------
// One padded counter buffer `pad` (stride S ints per counter, S*4 bytes apart
// to spread atomic traffic across cache lines) serves as:
//   phase 1: degree histogram (count_deg4)
//   phase 2: scatter cursor   (initialized to exclusive-scan by scan_pass3)

// count in-degrees for both graphs, 4 edges per thread (ILP)
__global__ __launch_bounds__(256) void count_deg4(const int* __restrict__ dst_n, int En,
                                                  const int* __restrict__ dst_r, int Er,
                                                  int* __restrict__ pad, int n, int S) {
    int base = (blockIdx.x * 256 + threadIdx.x) * 4;
    #pragma unroll
    for (int j = 0; j < 4; ++j) {
        int i = base + j;
        if (i < En) {
            atomicAdd(&pad[dst_n[i] * S], 1);
        } else if (i < En + Er) {
            atomicAdd(&pad[(n + dst_r[i - En]) * S], 1);
        }
    }
}

// dis = rsqrt(deg+1)  (self loop)
__global__ __launch_bounds__(256) void compute_dis(const int* __restrict__ pad, int S,
                                                   float* __restrict__ dis2, int len) {
    int i = blockIdx.x * 256 + threadIdx.x;
    if (i < len) dis2[i] = rsqrtf((float)(pad[i * S] + 1));
}

// scan pass 1: per-1024-chunk sums.  grid = 2*nb blocks (two graphs).
__global__ __launch_bounds__(1024) void scan_pass1(const int* __restrict__ pad, int S,
                                                   int* __restrict__ bsum2, int n, int nb) {
    int g = blockIdx.x / nb, b = blockIdx.x % nb;
    int i = b * 1024 + threadIdx.x;
    int v = (i < n) ? pad[(g * n + i) * S] : 0;
    #pragma unroll
    for (int off = 32; off; off >>= 1) v += __shfl_down(v, off, 64);
    __shared__ int wsum[16];
    int lane = threadIdx.x & 63, wid = threadIdx.x >> 6;
    if (lane == 0) wsum[wid] = v;
    __syncthreads();
    if (threadIdx.x == 0) {
        int s = 0;
        for (int w = 0; w < 16; ++w) s += wsum[w];
        bsum2[g * 64 + b] = s;
    }
}

// scan pass 2: exclusive-scan the <=64 chunk sums per graph
__global__ __launch_bounds__(128) void scan_pass2(int* __restrict__ bsum2, int nb) {
    int wid = threadIdx.x >> 6, lane = threadIdx.x & 63;
    int v = (lane < nb) ? bsum2[wid * 64 + lane] : 0;
    int incl = v;
    #pragma unroll
    for (int off = 1; off < 64; off <<= 1) {
        int t = __shfl_up(incl, off, 64);
        if (lane >= off) incl += t;
    }
    if (lane < nb) bsum2[wid * 64 + lane] = incl - v;  // exclusive
}

// scan pass 3: full exclusive scan -> rs (dense) + cursor (into pad, padded)
__global__ __launch_bounds__(1024) void scan_pass3(int* __restrict__ pad, int S,
                                                   const int* __restrict__ bsum2,
                                                   int* __restrict__ rs2,
                                                   int n, int nb, int En, int Er) {
    int g = blockIdx.x / nb, b = blockIdx.x % nb;
    int i = b * 1024 + threadIdx.x;
    int v = (i < n) ? pad[(g * n + i) * S] : 0;
    int lane = threadIdx.x & 63, wid = threadIdx.x >> 6;
    int incl = v;
    #pragma unroll
    for (int off = 1; off < 64; off <<= 1) {
        int t = __shfl_up(incl, off, 64);
        if (lane >= off) incl += t;
    }
    __shared__ int wsum[16];
    if (lane == 63) wsum[wid] = incl;
    __syncthreads();
    if (threadIdx.x == 0) {
        int s = 0;
        for (int w = 0; w < 16; ++w) { int t = wsum[w]; wsum[w] = s; s += t; }
    }
    __syncthreads();
    int excl = incl - v + wsum[wid] + bsum2[g * 64 + b];
    if (i < n) {
        rs2[g * (n + 1) + i] = excl;
        pad[(g * n + i) * S] = excl;  // becomes the scatter cursor
    }
    if (i == 0) rs2[g * (n + 1) + n] = g ? Er : En;
}

// scatter src ids into CSR slots, 4 edges per thread (ILP)
template <typename IT>
__global__ __launch_bounds__(256) void scatter4(const int* __restrict__ src_n,
                                                const int* __restrict__ dst_n, int En,
                                                const int* __restrict__ src_r,
                                                const int* __restrict__ dst_r, int Er,
                                                int* __restrict__ pad, int S,
                                                IT* __restrict__ csr_n,
                                                IT* __restrict__ csr_r, int n) {
    int base = (blockIdx.x * 256 + threadIdx.x) * 4;
    #pragma unroll
    for (int j = 0; j < 4; ++j) {
        int i = base + j;
        if (i < En) {
            int p = atomicAdd(&pad[dst_n[i] * S], 1);
            csr_n[p] = (IT)src_n[i];
        } else if (i < En + Er) {
            int k = i - En;
            int p = atomicAdd(&pad[(n + dst_r[k]) * S], 1);
            csr_r[p] = (IT)src_r[k];
        }
    }
}

// ---------------- per-layer kernels ----------------

// Y[v,:] = dis[v] * (X[v,:] @ W).  128x128 tile, 8x8 register tile per thread.
__global__ __launch_bounds__(256) void gemm_scale(const float* __restrict__ X,
                                                  const float* __restrict__ W,
                                                  const float* __restrict__ dis,
                                                  float* __restrict__ Y, int n) {
    __shared__ float sX[128 * D];  // 64 KB
    int t = threadIdx.x;
    int rg = t >> 4;          // 16 row groups of 8 rows
    int cg = (t & 15) << 3;   // 16 col groups of 8 cols
    int rb = blockIdx.x * 128;
    int rows = min(128, n - rb);

    float4* sX4 = (float4*)sX;
    for (int i = t; i < rows * 32; i += 256)
        sX4[i] = ((const float4*)X)[(size_t)rb * 32 + i];
    __syncthreads();

    float acc[8][8] = {};
    #pragma unroll 2
    for (int k0 = 0; k0 < D; k0 += 4) {
        float4 xr[8];
        #pragma unroll
        for (int r = 0; r < 8; ++r)
            xr[r] = *(const float4*)&sX[(rg * 8 + r) * D + k0];
        #pragma unroll
        for (int j = 0; j < 4; ++j) {
            float4 wa = *(const float4*)(W + (size_t)(k0 + j) * D + cg);
            float4 wb = *(const float4*)(W + (size_t)(k0 + j) * D + cg + 4);
            #pragma unroll
            for (int r = 0; r < 8; ++r) {
                float xv = ((const float*)&xr[r])[j];
                acc[r][0] += xv * wa.x; acc[r][1] += xv * wa.y;
                acc[r][2] += xv * wa.z; acc[r][3] += xv * wa.w;
                acc[r][4] += xv * wb.x; acc[r][5] += xv * wb.y;
                acc[r][6] += xv * wb.z; acc[r][7] += xv * wb.w;
            }
        }
    }
    #pragma unroll
    for (int r = 0; r < 8; ++r) {
        int row = rb + rg * 8 + r;
        if (row < n) {
            float dv = dis[row];
            float4 o0, o1;
            o0.x = acc[r][0] * dv; o0.y = acc[r][1] * dv;
            o0.z = acc[r][2] * dv; o0.w = acc[r][3] * dv;
            o1.x = acc[r][4] * dv; o1.y = acc[r][5] * dv;
            o1.z = acc[r][6] * dv; o1.w = acc[r][7] * dv;
            *(float4*)(Y + (size_t)row * D + cg) = o0;
            *(float4*)(Y + (size_t)row * D + cg + 4) = o1;
        }
    }
}

// out[v,:] = maybe_relu( dis[v] * (sum_{e in CSR(v)} g[src_e,:] + g[v,:]) + bias )
// one 64-lane wave per node; edge ids loaded 64-wide then shfl-broadcast.
template <typename IT>
__global__ __launch_bounds__(256) void aggregate(const float* __restrict__ g,
                                                 const int* __restrict__ rs,
                                                 const IT* __restrict__ csr,
                                                 const float* __restrict__ dis,
                                                 const float* __restrict__ bias,
                                                 float* __restrict__ out, int n, int do_relu) {
    int v = blockIdx.x * 4 + (threadIdx.x >> 6);
    if (v >= n) return;
    int lane = threadIdx.x & 63;
    const float2* g2 = (const float2*)g;
    float2 acc = g2[(size_t)v * 64 + lane];  // self loop (g already dis-scaled)
    int e = rs[v], end = rs[v + 1];
    while (e < end) {
        int sid = (e + lane < end) ? (int)csr[e + lane] : 0;
        int m = min(64, end - e);
        int j = 0;
        for (; j + 3 < m; j += 4) {
            int s0 = __shfl(sid, j, 64);
            int s1 = __shfl(sid, j + 1, 64);
            int s2 = __shfl(sid, j + 2, 64);
            int s3 = __shfl(sid, j + 3, 64);
            float2 m0 = g2[(size_t)s0 * 64 + lane];
            float2 m1 = g2[(size_t)s1 * 64 + lane];
            float2 m2 = g2[(size_t)s2 * 64 + lane];
            float2 m3 = g2[(size_t)s3 * 64 + lane];
            acc.x += m0.x + m1.x + m2.x + m3.x;
            acc.y += m0.y + m1.y + m2.y + m3.y;
        }
        for (; j < m; ++j) {
            int s = __shfl(sid, j, 64);
            float2 mm = g2[(size_t)s * 64 + lane];
            acc.x += mm.x;
            acc.y += mm.y;
        }
        e += m;
    }
    float dv = dis[v];
    float2 bb = ((const float2*)bias)[lane];
    float ox = dv * acc.x + bb.x;
    float oy = dv * acc.y + bb.y;
    if (do_relu) { ox = fmaxf(ox, 0.f); oy = fmaxf(oy, 0.f); }
    ((float2*)out)[(size_t)v * 64 + lane] = make_float2(ox, oy);
}

// ---------------- host launcher ----------------

template <typename IT>
static void run_pipeline(const float* x, const float* W_role, const float* b_role,
                         const float* W2, const float* b2, const float* W1, const float* b1,
                         const int* src_n, const int* dst_n, int En,
                         const int* src_r, const int* dst_r, int Er,
                         int n, void* d_ws, size_t ws_size, float* out, hipStream_t stream) {
    // pick the largest counter stride (in ints) whose footprint fits the workspace
    size_t fixed = ((size_t)n * D * 4 + 255 & ~(size_t)255)              // g
                 + ((size_t)2 * n * 4 + 255 & ~(size_t)255)              // dis2
                 + ((size_t)2 * (n + 1) * 4 + 255 & ~(size_t)255)        // rs2
                 + 512                                                    // bsum2
                 + ((size_t)(En + Er) * sizeof(IT) + 255 & ~(size_t)255); // csr
    int S = 1;
    for (int cand = 16; cand >= 1; cand >>= 1) {
        if (fixed + (size_t)2 * n * cand * 4 + 256 <= ws_size) { S = cand; break; }
    }

    char* p = (char*)d_ws;
    auto alloc = [&](size_t bytes) { char* r = p; p += (bytes + 255) & ~(size_t)255; return r; };
    float* g    = (float*)alloc((size_t)n * D * sizeof(float));
    float* dis2 = (float*)alloc((size_t)2 * n * sizeof(float));
    int*   rs2  = (int*)alloc((size_t)2 * (n + 1) * sizeof(int));
    int*   bsum2= (int*)alloc(512);
    IT*    csr  = (IT*)alloc((size_t)(En + Er) * sizeof(IT));
    int*   pad  = (int*)alloc((size_t)2 * n * S * sizeof(int));
    float* dis_n = dis2;
    float* dis_r = dis2 + n;
    int*   rs_n  = rs2;
    int*   rs_r  = rs2 + (n + 1);
    IT*    csr_n = csr;
    IT*    csr_r = csr + En;

    int nb = (n + 1023) / 1024;  // must be <= 64 (n <= 65536)
    int E4 = (En + Er + 3) / 4;

    hipMemsetAsync(pad, 0, (size_t)2 * n * S * sizeof(int), stream);
    count_deg4<<<(E4 + 255) / 256, 256, 0, stream>>>(dst_n, En, dst_r, Er, pad, n, S);
    compute_dis<<<(2 * n + 255) / 256, 256, 0, stream>>>(pad, S, dis2, 2 * n);
    scan_pass1<<<2 * nb, 1024, 0, stream>>>(pad, S, bsum2, n, nb);
    scan_pass2<<<1, 128, 0, stream>>>(bsum2, nb);
    scan_pass3<<<2 * nb, 1024, 0, stream>>>(pad, S, bsum2, rs2, n, nb, En, Er);
    scatter4<IT><<<(E4 + 255) / 256, 256, 0, stream>>>(src_n, dst_n, En, src_r, dst_r, Er,
                                                       pad, S, csr_n, csr_r, n);

    int gblk = (n + 127) / 128;
    int ablk = (n + 3) / 4;
    // layer 1: role graph, relu (out doubles as h scratch)
    gemm_scale<<<gblk, 256, 0, stream>>>(x, W_role, dis_r, g, n);
    aggregate<IT><<<ablk, 256, 0, stream>>>(g, rs_r, csr_r, dis_r, b_role, out, n, 1);
    // layer 2: normal graph, relu
    gemm_scale<<<gblk, 256, 0, stream>>>(out, W2, dis_n, g, n);
    aggregate<IT><<<ablk, 256, 0, stream>>>(g, rs_n, csr_n, dis_n, b2, out, n, 1);
    // layer 3: normal graph, no relu
    gemm_scale<<<gblk, 256, 0, stream>>>(out, W1, dis_n, g, n);
    aggregate<IT><<<ablk, 256, 0, stream>>>(g, rs_n, csr_n, dis_n, b1, out, n, 0);
}

extern "C" void kernel_launch(void* const* d_in, const int* in_sizes, int n_in,
                              void* d_out, int out_size, void* d_ws, size_t ws_size,
                              hipStream_t stream) {
    const float* x      = (const float*)d_in[0];
    const float* W_role = (const float*)d_in[1];
    const float* b_role = (const float*)d_in[2];
    const float* W2     = (const float*)d_in[3];
    const float* b2     = (const float*)d_in[4];
    const float* W1     = (const float*)d_in[5];
    const float* b1     = (const float*)d_in[6];
    const int*   ein    = (const int*)d_in[7];
    const int*   eir    = (const int*)d_in[8];

    int n  = in_sizes[0] / D;   // 50000
    int En = in_sizes[7] / 2;   // 640000
    int Er = in_sizes[8] / 2;   // 640000
    const int* src_n = ein;
    const int* dst_n = ein + En;
    const int* src_r = eir;
    const int* dst_r = eir + Er;
    float* out = (float*)d_out;

    if (n <= 65535) {
        run_pipeline<unsigned short>(x, W_role, b_role, W2, b2, W1, b1,
                                     src_n, dst_n, En, src_r, dst_r, Er,
                                     n, d_ws, ws_size, out, stream);
    } else {
        run_pipeline<int>(x, W_role, b_role, W2, b2, W1, b1,
                          src_n, dst_n, En, src_r, dst_r, Er,
                          n, d_ws, ws_size, out, stream);
    }
}

// Round 3
// 368.731 us; speedup vs baseline: 1.3126x; 1.2649x over previous
//
#include <hip/hip_runtime.h>

#define D 128
#define CHUNK 8192     // edges per partition block
#define BSH 7          // 128 nodes per bucket
#define BNODES 128
#define MAXNB 512      // supports n <= 65536
#define CAP 6144       // LDS CSR staging capacity (avg bucket ~1640 edges)

// ---------------- P1: per-(graph,chunk) bucket histogram ----------------
__global__ __launch_bounds__(256) void p1_hist(const int* __restrict__ dst_n,
                                               const int* __restrict__ dst_r,
                                               int En, int Er,
                                               int* __restrict__ base2,
                                               int NB, int NC, int L) {
    int g = blockIdx.x / NC, c = blockIdx.x % NC;
    const int* dst = g ? dst_r : dst_n;
    int E = g ? Er : En;
    __shared__ int hist[MAXNB];
    for (int i = threadIdx.x; i < NB; i += 256) hist[i] = 0;
    __syncthreads();
    int e0 = c * CHUNK, e1 = min(e0 + CHUNK, E);
    for (int e = e0 + threadIdx.x; e < e1; e += 256)
        atomicAdd(&hist[dst[e] >> BSH], 1);
    __syncthreads();
    for (int b = threadIdx.x; b < NB; b += 256)
        base2[g * L + b * NC + c] = hist[b];  // bucket-major for stable partition scan
}

// ---------------- 3-pass exclusive scan over base2[2][L], in place ----------------
__global__ __launch_bounds__(1024) void scan_pass1(const int* __restrict__ data,
                                                   int* __restrict__ bsum2, int L, int nb) {
    int g = blockIdx.x / nb, b = blockIdx.x % nb;
    int i = b * 1024 + threadIdx.x;
    int v = (i < L) ? data[g * L + i] : 0;
    #pragma unroll
    for (int off = 32; off; off >>= 1) v += __shfl_down(v, off, 64);
    __shared__ int wsum[16];
    int lane = threadIdx.x & 63, wid = threadIdx.x >> 6;
    if (lane == 0) wsum[wid] = v;
    __syncthreads();
    if (threadIdx.x == 0) {
        int s = 0;
        for (int w = 0; w < 16; ++w) s += wsum[w];
        bsum2[g * 64 + b] = s;
    }
}

__global__ __launch_bounds__(128) void scan_pass2(int* __restrict__ bsum2, int nb) {
    int wid = threadIdx.x >> 6, lane = threadIdx.x & 63;
    int v = (lane < nb) ? bsum2[wid * 64 + lane] : 0;
    int incl = v;
    #pragma unroll
    for (int off = 1; off < 64; off <<= 1) {
        int t = __shfl_up(incl, off, 64);
        if (lane >= off) incl += t;
    }
    if (lane < nb) bsum2[wid * 64 + lane] = incl - v;
}

__global__ __launch_bounds__(1024) void scan_pass3(int* __restrict__ data,
                                                   const int* __restrict__ bsum2,
                                                   int L, int nb) {
    int g = blockIdx.x / nb, b = blockIdx.x % nb;
    int i = b * 1024 + threadIdx.x;
    int v = (i < L) ? data[g * L + i] : 0;
    int lane = threadIdx.x & 63, wid = threadIdx.x >> 6;
    int incl = v;
    #pragma unroll
    for (int off = 1; off < 64; off <<= 1) {
        int t = __shfl_up(incl, off, 64);
        if (lane >= off) incl += t;
    }
    __shared__ int wsum[16];
    if (lane == 63) wsum[wid] = incl;
    __syncthreads();
    if (threadIdx.x == 0) {
        int s = 0;
        for (int w = 0; w < 16; ++w) { int t = wsum[w]; wsum[w] = s; s += t; }
    }
    __syncthreads();
    if (i < L) data[g * L + i] = incl - v + wsum[wid] + bsum2[g * 64 + b];
}

// ---------------- P2: partition edges into bucket-contiguous runs ----------------
// part entry = (dst<<16) | src   (requires n <= 65536)
__global__ __launch_bounds__(256) void p2_scatter(const int* __restrict__ src_n,
                                                  const int* __restrict__ dst_n,
                                                  const int* __restrict__ src_r,
                                                  const int* __restrict__ dst_r,
                                                  int En, int Er,
                                                  const int* __restrict__ base2,
                                                  unsigned int* __restrict__ part_n,
                                                  unsigned int* __restrict__ part_r,
                                                  int NB, int NC, int L) {
    int g = blockIdx.x / NC, c = blockIdx.x % NC;
    const int* src = g ? src_r : src_n;
    const int* dst = g ? dst_r : dst_n;
    unsigned int* part = g ? part_r : part_n;
    int E = g ? Er : En;
    __shared__ int cur[MAXNB];
    for (int b = threadIdx.x; b < NB; b += 256)
        cur[b] = base2[g * L + b * NC + c];
    __syncthreads();
    int e0 = c * CHUNK, e1 = min(e0 + CHUNK, E);
    for (int e = e0 + threadIdx.x; e < e1; e += 256) {
        int d = dst[e];
        int pos = atomicAdd(&cur[d >> BSH], 1);
        part[pos] = ((unsigned)d << 16) | (unsigned)src[e];
    }
}

// ---------------- P3: per-bucket CSR build (all-LDS) + deg/dis ----------------
__global__ __launch_bounds__(256) void p3_csr(const unsigned int* __restrict__ part_n,
                                              const unsigned int* __restrict__ part_r,
                                              const int* __restrict__ base2,
                                              int* __restrict__ rs2,
                                              float* __restrict__ dis2,
                                              unsigned short* __restrict__ csr_n,
                                              unsigned short* __restrict__ csr_r,
                                              int n, int NB, int NC, int L, int En, int Er) {
    int g = blockIdx.x / NB, b = blockIdx.x % NB;
    const unsigned int* part = g ? part_r : part_n;
    unsigned short* csr = g ? csr_r : csr_n;
    int E = g ? Er : En;
    __shared__ int deg[BNODES];
    __shared__ int cur[BNODES];
    __shared__ unsigned short buf[CAP];
    __shared__ int w0tot;
    int t = threadIdx.x;
    if (t < BNODES) deg[t] = 0;
    __syncthreads();
    int bstart = base2[g * L + b * NC];
    int bend = (b + 1 < NB) ? base2[g * L + (b + 1) * NC] : E;
    int sz = bend - bstart;
    for (int e = bstart + t; e < bend; e += 256)
        atomicAdd(&deg[(part[e] >> 16) & (BNODES - 1)], 1);
    __syncthreads();
    int incl = 0, v = 0;
    if (t < BNODES) {  // waves 0,1 fully active: safe shfl scan
        int lane = t & 63;
        v = deg[t];
        incl = v;
        #pragma unroll
        for (int off = 1; off < 64; off <<= 1) {
            int tt = __shfl_up(incl, off, 64);
            if (lane >= off) incl += tt;
        }
        if (t == 63) w0tot = incl;
    }
    __syncthreads();
    if (t < BNODES) {
        int excl = incl - v + ((t >= 64) ? w0tot : 0);
        cur[t] = excl;
        int idx = b * BNODES + t;
        if (idx < n) {
            rs2[g * (n + 1) + idx] = bstart + excl;
            dis2[g * n + idx] = rsqrtf((float)(deg[t] + 1));
        }
    }
    if (b == NB - 1 && t == 255) rs2[g * (n + 1) + n] = E;
    __syncthreads();
    if (sz <= CAP) {
        for (int e = bstart + t; e < bend; e += 256) {
            unsigned int p = part[e];
            int pos = atomicAdd(&cur[(p >> 16) & (BNODES - 1)], 1);
            buf[pos] = (unsigned short)(p & 0xffffu);
        }
        __syncthreads();
        for (int i = t; i < sz; i += 256) csr[bstart + i] = buf[i];  // coalesced
    } else {  // oversized bucket fallback (never hit at this scale)
        for (int e = bstart + t; e < bend; e += 256) {
            unsigned int p = part[e];
            int pos = atomicAdd(&cur[(p >> 16) & (BNODES - 1)], 1);
            csr[bstart + pos] = (unsigned short)(p & 0xffffu);
        }
    }
}

// ---------------- per-layer kernels (unchanged from R2) ----------------

__global__ __launch_bounds__(256) void gemm_scale(const float* __restrict__ X,
                                                  const float* __restrict__ W,
                                                  const float* __restrict__ dis,
                                                  float* __restrict__ Y, int n) {
    __shared__ float sX[128 * D];
    int t = threadIdx.x;
    int rg = t >> 4;
    int cg = (t & 15) << 3;
    int rb = blockIdx.x * 128;
    int rows = min(128, n - rb);

    float4* sX4 = (float4*)sX;
    for (int i = t; i < rows * 32; i += 256)
        sX4[i] = ((const float4*)X)[(size_t)rb * 32 + i];
    __syncthreads();

    float acc[8][8] = {};
    #pragma unroll 2
    for (int k0 = 0; k0 < D; k0 += 4) {
        float4 xr[8];
        #pragma unroll
        for (int r = 0; r < 8; ++r)
            xr[r] = *(const float4*)&sX[(rg * 8 + r) * D + k0];
        #pragma unroll
        for (int j = 0; j < 4; ++j) {
            float4 wa = *(const float4*)(W + (size_t)(k0 + j) * D + cg);
            float4 wb = *(const float4*)(W + (size_t)(k0 + j) * D + cg + 4);
            #pragma unroll
            for (int r = 0; r < 8; ++r) {
                float xv = ((const float*)&xr[r])[j];
                acc[r][0] += xv * wa.x; acc[r][1] += xv * wa.y;
                acc[r][2] += xv * wa.z; acc[r][3] += xv * wa.w;
                acc[r][4] += xv * wb.x; acc[r][5] += xv * wb.y;
                acc[r][6] += xv * wb.z; acc[r][7] += xv * wb.w;
            }
        }
    }
    #pragma unroll
    for (int r = 0; r < 8; ++r) {
        int row = rb + rg * 8 + r;
        if (row < n) {
            float dv = dis[row];
            float4 o0, o1;
            o0.x = acc[r][0] * dv; o0.y = acc[r][1] * dv;
            o0.z = acc[r][2] * dv; o0.w = acc[r][3] * dv;
            o1.x = acc[r][4] * dv; o1.y = acc[r][5] * dv;
            o1.z = acc[r][6] * dv; o1.w = acc[r][7] * dv;
            *(float4*)(Y + (size_t)row * D + cg) = o0;
            *(float4*)(Y + (size_t)row * D + cg + 4) = o1;
        }
    }
}

__global__ __launch_bounds__(256) void aggregate(const float* __restrict__ g,
                                                 const int* __restrict__ rs,
                                                 const unsigned short* __restrict__ csr,
                                                 const float* __restrict__ dis,
                                                 const float* __restrict__ bias,
                                                 float* __restrict__ out, int n, int do_relu) {
    int v = blockIdx.x * 4 + (threadIdx.x >> 6);
    if (v >= n) return;
    int lane = threadIdx.x & 63;
    const float2* g2 = (const float2*)g;
    float2 acc = g2[(size_t)v * 64 + lane];  // self loop (g pre-scaled by dis)
    int e = rs[v], end = rs[v + 1];
    while (e < end) {
        int sid = (e + lane < end) ? (int)csr[e + lane] : 0;
        int m = min(64, end - e);
        int j = 0;
        for (; j + 3 < m; j += 4) {
            int s0 = __shfl(sid, j, 64);
            int s1 = __shfl(sid, j + 1, 64);
            int s2 = __shfl(sid, j + 2, 64);
            int s3 = __shfl(sid, j + 3, 64);
            float2 m0 = g2[(size_t)s0 * 64 + lane];
            float2 m1 = g2[(size_t)s1 * 64 + lane];
            float2 m2 = g2[(size_t)s2 * 64 + lane];
            float2 m3 = g2[(size_t)s3 * 64 + lane];
            acc.x += m0.x + m1.x + m2.x + m3.x;
            acc.y += m0.y + m1.y + m2.y + m3.y;
        }
        for (; j < m; ++j) {
            int s = __shfl(sid, j, 64);
            float2 mm = g2[(size_t)s * 64 + lane];
            acc.x += mm.x;
            acc.y += mm.y;
        }
        e += m;
    }
    float dv = dis[v];
    float2 bb = ((const float2*)bias)[lane];
    float ox = dv * acc.x + bb.x;
    float oy = dv * acc.y + bb.y;
    if (do_relu) { ox = fmaxf(ox, 0.f); oy = fmaxf(oy, 0.f); }
    ((float2*)out)[(size_t)v * 64 + lane] = make_float2(ox, oy);
}

// ---------------- host launcher ----------------

extern "C" void kernel_launch(void* const* d_in, const int* in_sizes, int n_in,
                              void* d_out, int out_size, void* d_ws, size_t ws_size,
                              hipStream_t stream) {
    const float* x      = (const float*)d_in[0];
    const float* W_role = (const float*)d_in[1];
    const float* b_role = (const float*)d_in[2];
    const float* W2     = (const float*)d_in[3];
    const float* b2     = (const float*)d_in[4];
    const float* W1     = (const float*)d_in[5];
    const float* b1     = (const float*)d_in[6];
    const int*   ein    = (const int*)d_in[7];
    const int*   eir    = (const int*)d_in[8];

    int n  = in_sizes[0] / D;   // 50000
    int En = in_sizes[7] / 2;   // 640000
    int Er = in_sizes[8] / 2;   // 640000
    const int* src_n = ein;
    const int* dst_n = ein + En;
    const int* src_r = eir;
    const int* dst_r = eir + Er;
    float* out = (float*)d_out;

    int NB = (n + BNODES - 1) >> BSH;                    // 391 buckets/graph
    int Emax = En > Er ? En : Er;
    int NC = (Emax + CHUNK - 1) / CHUNK;                 // 79 chunks/graph
    int L  = NB * NC;                                    // 30889 (must be <= 65536)
    int nb_scan = (L + 1023) / 1024;                     // 31 (must be <= 64)

    char* p = (char*)d_ws;
    auto alloc = [&](size_t bytes) { char* r = p; p += (bytes + 255) & ~(size_t)255; return r; };
    float*          gbuf   = (float*)alloc((size_t)n * D * sizeof(float));        // 25.6 MB
    float*          dis2   = (float*)alloc((size_t)2 * n * sizeof(float));
    int*            rs2    = (int*)alloc((size_t)2 * (n + 1) * sizeof(int));
    int*            base2  = (int*)alloc((size_t)2 * L * sizeof(int));
    int*            bsum2  = (int*)alloc(512);
    unsigned int*   part_n = (unsigned int*)alloc((size_t)En * sizeof(unsigned int));
    unsigned int*   part_r = (unsigned int*)alloc((size_t)Er * sizeof(unsigned int));
    unsigned short* csr    = (unsigned short*)alloc((size_t)(En + Er) * sizeof(unsigned short));
    float* dis_n = dis2;
    float* dis_r = dis2 + n;
    int*   rs_n  = rs2;
    int*   rs_r  = rs2 + (n + 1);
    unsigned short* csr_n = csr;
    unsigned short* csr_r = csr + En;

    // ---- graph preprocessing: histogram -> scan -> partition -> bucket CSR ----
    p1_hist<<<2 * NC, 256, 0, stream>>>(dst_n, dst_r, En, Er, base2, NB, NC, L);
    scan_pass1<<<2 * nb_scan, 1024, 0, stream>>>(base2, bsum2, L, nb_scan);
    scan_pass2<<<1, 128, 0, stream>>>(bsum2, nb_scan);
    scan_pass3<<<2 * nb_scan, 1024, 0, stream>>>(base2, bsum2, L, nb_scan);
    p2_scatter<<<2 * NC, 256, 0, stream>>>(src_n, dst_n, src_r, dst_r, En, Er,
                                           base2, part_n, part_r, NB, NC, L);
    p3_csr<<<2 * NB, 256, 0, stream>>>(part_n, part_r, base2, rs2, dis2,
                                       csr_n, csr_r, n, NB, NC, L, En, Er);

    // ---- 3 GCN layers; d_out doubles as the h scratch buffer ----
    int gblk = (n + 127) / 128;
    int ablk = (n + 3) / 4;
    gemm_scale<<<gblk, 256, 0, stream>>>(x, W_role, dis_r, gbuf, n);
    aggregate<<<ablk, 256, 0, stream>>>(gbuf, rs_r, csr_r, dis_r, b_role, out, n, 1);
    gemm_scale<<<gblk, 256, 0, stream>>>(out, W2, dis_n, gbuf, n);
    aggregate<<<ablk, 256, 0, stream>>>(gbuf, rs_n, csr_n, dis_n, b2, out, n, 1);
    gemm_scale<<<gblk, 256, 0, stream>>>(out, W1, dis_n, gbuf, n);
    aggregate<<<ablk, 256, 0, stream>>>(gbuf, rs_n, csr_n, dis_n, b1, out, n, 0);
}